// Round 8
// baseline (163.366 us; speedup 1.0000x reference)
//
#include <hip/hip_runtime.h>
#include <math.h>

#define Bb 4
#define Cc 32
#define Nn 200
#define Tt 2048
#define Ss 24
#define EPSf 1e-5f
#define GRID 512
#define RKEEP 40   // rows kept in registers (of 50 per block)

typedef float f4 __attribute__((ext_vector_type(4)));
typedef int i4 __attribute__((ext_vector_type(4)));

__device__ __forceinline__ unsigned rne_bf16(float f) {
    unsigned u = __float_as_uint(f);
    return (u + 0x7FFFu + ((u >> 16) & 1u)) >> 16;
}
__device__ __forceinline__ unsigned pack2(float a, float b) {
    return rne_bf16(a) | (rne_bf16(b) << 16);
}
__device__ __forceinline__ float lo16(unsigned u) { return __uint_as_float(u << 16); }
__device__ __forceinline__ float hi16(unsigned u) { return __uint_as_float(u & 0xFFFF0000u); }

// ws: float2 part[32*24*16] (96 KiB) | int cntp[4*24] | pad | int counter

__global__ void k_zero(int* __restrict__ counter) { *counter = 0; }

__global__ __launch_bounds__(256, 2) void k_fused(const float* __restrict__ x,
                                                  const int* __restrict__ timei,
                                                  float2* __restrict__ part,
                                                  int* __restrict__ cntp,
                                                  int* __restrict__ counter,
                                                  float* __restrict__ out) {
    __shared__ float lsum[Ss], lsq[Ss];
    __shared__ int   lcnt[Ss];
    __shared__ float s_r[Ss], s_mr[Ss];

    const int tid = threadIdx.x;
    const int bx  = blockIdx.x;
    const int b   = bx >> 7;          // 4
    const int c   = (bx >> 2) & 31;   // 32
    const int q   = bx & 3;           // 4 chunks of 50 rows
    const bool do_hist = (c == 0 && q == 0);

    if (tid < Ss) { lsum[tid] = 0.f; lsq[tid] = 0.f; lcnt[tid] = 0; }
    __syncthreads();

    const int t0 = tid * 4;
    const i4 sl0 = *(const i4*)(timei + b * Tt + t0);
    const i4 sl1 = *(const i4*)(timei + b * Tt + t0 + 1024);

    const size_t plane = ((size_t)(b * Cc + c) * Nn + (size_t)q * 50) * Tt;
    const float* bp = x + plane + t0;

    unsigned xb[RKEEP * 4];           // 160 packed-bf16 VGPRs
    float s0=0,s1=0,s2=0,s3=0,s4=0,s5=0,s6=0,s7=0;
    float q0=0,q1=0,q2=0,q3=0,q4=0,q5=0,q6=0,q7=0;

#pragma unroll
    for (int r = 0; r < 50; ++r) {
        f4 v0 = *(const f4*)(bp + (size_t)r * Tt);          // normal: allocate L3
        f4 v1 = *(const f4*)(bp + (size_t)r * Tt + 1024);
        if (r < RKEEP) {
            xb[r*4+0] = pack2(v0[0], v0[1]);
            xb[r*4+1] = pack2(v0[2], v0[3]);
            xb[r*4+2] = pack2(v1[0], v1[1]);
            xb[r*4+3] = pack2(v1[2], v1[3]);
        }
        s0 += v0[0]; q0 += v0[0]*v0[0];
        s1 += v0[1]; q1 += v0[1]*v0[1];
        s2 += v0[2]; q2 += v0[2]*v0[2];
        s3 += v0[3]; q3 += v0[3]*v0[3];
        s4 += v1[0]; q4 += v1[0]*v1[0];
        s5 += v1[1]; q5 += v1[1]*v1[1];
        s6 += v1[2]; q6 += v1[2]*v1[2];
        s7 += v1[3]; q7 += v1[3]*v1[3];
    }

    atomicAdd(&lsum[sl0[0]], s0); atomicAdd(&lsq[sl0[0]], q0);
    atomicAdd(&lsum[sl0[1]], s1); atomicAdd(&lsq[sl0[1]], q1);
    atomicAdd(&lsum[sl0[2]], s2); atomicAdd(&lsq[sl0[2]], q2);
    atomicAdd(&lsum[sl0[3]], s3); atomicAdd(&lsq[sl0[3]], q3);
    atomicAdd(&lsum[sl1[0]], s4); atomicAdd(&lsq[sl1[0]], q4);
    atomicAdd(&lsum[sl1[1]], s5); atomicAdd(&lsq[sl1[1]], q5);
    atomicAdd(&lsum[sl1[2]], s6); atomicAdd(&lsq[sl1[2]], q6);
    atomicAdd(&lsum[sl1[3]], s7); atomicAdd(&lsq[sl1[3]], q7);
    if (do_hist) {
        atomicAdd(&lcnt[sl0[0]], 1); atomicAdd(&lcnt[sl0[1]], 1);
        atomicAdd(&lcnt[sl0[2]], 1); atomicAdd(&lcnt[sl0[3]], 1);
        atomicAdd(&lcnt[sl1[0]], 1); atomicAdd(&lcnt[sl1[1]], 1);
        atomicAdd(&lcnt[sl1[2]], 1); atomicAdd(&lcnt[sl1[3]], 1);
    }
    __syncthreads();

    if (tid < Ss) {
        part[(c * Ss + tid) * 16 + (b * 4 + q)] = make_float2(lsum[tid], lsq[tid]);
        if (do_hist) cntp[b * Ss + tid] = lcnt[tid];
    }

    // ---- software grid barrier (all 512 blocks co-resident: 2/CU at <=256 VGPR) ----
    if (tid == 0) {
        __hip_atomic_fetch_add(counter, 1, __ATOMIC_ACQ_REL, __HIP_MEMORY_SCOPE_AGENT);
        while (__hip_atomic_load(counter, __ATOMIC_ACQUIRE, __HIP_MEMORY_SCOPE_AGENT) < GRID)
            __builtin_amdgcn_s_sleep(2);
    }
    __syncthreads();

    // ---- final stats for this block's c ----
    if (tid < Ss) { lsum[tid] = 0.f; lsq[tid] = 0.f; }
    __syncthreads();
    if (tid < 192) {                  // 24 slots x 8 lanes, 2 chunks each
        const int s = tid >> 3, j = tid & 7;
        float2 p0 = part[(c * Ss + s) * 16 + 2 * j];
        float2 p1 = part[(c * Ss + s) * 16 + 2 * j + 1];
        atomicAdd(&lsum[s], p0.x + p1.x);
        atomicAdd(&lsq[s],  p0.y + p1.y);
    }
    __syncthreads();
    if (tid < Ss) {
        int cnt = cntp[tid] + cntp[Ss + tid] + cntp[2 * Ss + tid] + cntp[3 * Ss + tid];
        float denom = fmaxf((float)cnt, 1e-12f) * (float)Nn;
        float m  = lsum[tid] / denom;
        float m2 = lsq[tid]  / denom;
        float rr = 1.0f / sqrtf(m2 - m * m + EPSf);
        s_r[tid]  = rr;
        s_mr[tid] = m * rr;
    }
    __syncthreads();

    const float rr0 = s_r[sl0[0]], mr0 = s_mr[sl0[0]];
    const float rr1 = s_r[sl0[1]], mr1 = s_mr[sl0[1]];
    const float rr2 = s_r[sl0[2]], mr2 = s_mr[sl0[2]];
    const float rr3 = s_r[sl0[3]], mr3 = s_mr[sl0[3]];
    const float rr4 = s_r[sl1[0]], mr4 = s_mr[sl1[0]];
    const float rr5 = s_r[sl1[1]], mr5 = s_mr[sl1[1]];
    const float rr6 = s_r[sl1[2]], mr6 = s_mr[sl1[2]];
    const float rr7 = s_r[sl1[3]], mr7 = s_mr[sl1[3]];

    float* op = out + plane + t0;
#pragma unroll
    for (int r = 0; r < RKEEP; ++r) {
        f4 o0, o1;
        o0[0] = fmaf(lo16(xb[r*4+0]), rr0, -mr0);
        o0[1] = fmaf(hi16(xb[r*4+0]), rr1, -mr1);
        o0[2] = fmaf(lo16(xb[r*4+1]), rr2, -mr2);
        o0[3] = fmaf(hi16(xb[r*4+1]), rr3, -mr3);
        o1[0] = fmaf(lo16(xb[r*4+2]), rr4, -mr4);
        o1[1] = fmaf(hi16(xb[r*4+2]), rr5, -mr5);
        o1[2] = fmaf(lo16(xb[r*4+3]), rr6, -mr6);
        o1[3] = fmaf(hi16(xb[r*4+3]), rr7, -mr7);
        __builtin_nontemporal_store(o0, (f4*)(op + (size_t)r * Tt));
        __builtin_nontemporal_store(o1, (f4*)(op + (size_t)r * Tt + 1024));
    }
#pragma unroll
    for (int r = RKEEP; r < 50; ++r) {   // last 10 rows: re-read (read last -> L3-warm)
        f4 v0 = *(const f4*)(bp + (size_t)r * Tt);
        f4 v1 = *(const f4*)(bp + (size_t)r * Tt + 1024);
        f4 o0, o1;
        o0[0] = fmaf(v0[0], rr0, -mr0);
        o0[1] = fmaf(v0[1], rr1, -mr1);
        o0[2] = fmaf(v0[2], rr2, -mr2);
        o0[3] = fmaf(v0[3], rr3, -mr3);
        o1[0] = fmaf(v1[0], rr4, -mr4);
        o1[1] = fmaf(v1[1], rr5, -mr5);
        o1[2] = fmaf(v1[2], rr6, -mr6);
        o1[3] = fmaf(v1[3], rr7, -mr7);
        __builtin_nontemporal_store(o0, (f4*)(op + (size_t)r * Tt));
        __builtin_nontemporal_store(o1, (f4*)(op + (size_t)r * Tt + 1024));
    }
}

extern "C" void kernel_launch(void* const* d_in, const int* in_sizes, int n_in,
                              void* d_out, int out_size, void* d_ws, size_t ws_size,
                              hipStream_t stream) {
    const float* x   = (const float*)d_in[0];
    const int* timei = (const int*)d_in[1];
    float* out = (float*)d_out;

    float2* part = (float2*)d_ws;                                   // 96 KiB
    int* cntp    = (int*)((char*)d_ws + (size_t)Cc * Ss * 16 * sizeof(float2));
    int* counter = (int*)((char*)d_ws + (size_t)Cc * Ss * 16 * sizeof(float2)
                          + 128 * sizeof(int));                     // own cacheline

    k_zero<<<1, 1, 0, stream>>>(counter);
    k_fused<<<GRID, 256, 0, stream>>>(x, timei, part, cntp, counter, out);
}